// Round 2
// baseline (1440.144 us; speedup 1.0000x reference)
//
#include <hip/hip_runtime.h>

// ContinuousGRULayer: B=512,T=512,D=32,H=64,L=2, fp32 exact.
// Strategy: sequential-scan RNN -> parallelism is batch only.
//   grid = 256 blocks (2 batch elems each), block = 256 threads.
//   thread (j = tid>>2 in [0,64), q = tid&3) : q = gate-role / k-chunk.
//   ALL weights live in per-thread registers (~176 VGPR of slices),
//   loaded once before the t-loop; LDS only carries h / r*h / x state.
//   Partial-dot reduction via __shfl_xor within 4-lane groups.
//   5 __syncthreads per timestep; h ping-pong buffered across timesteps.

#define NBATCH 512
#define NT     512
#define ND     32
#define NH     64
#define NL     2
#define AALPHA 0.4f   // 2/5
#define ABETA  0.8f   // 4/5

__device__ __forceinline__ float sigm(float v) {
    return __builtin_amdgcn_rcpf(1.0f + __expf(-v));
}
__device__ __forceinline__ float tanh_(float v) {
    // tanh(x) = 1 - 2/(1+e^{2x});  e^inf -> rcp=0 -> 1; e^-inf -> 1-2 = -1
    return 1.0f - 2.0f * __builtin_amdgcn_rcpf(1.0f + __expf(2.0f * v));
}

__global__ __launch_bounds__(256, 1) void cgru_fused(
    const float* __restrict__ x, const float* __restrict__ tin,
    const float* __restrict__ Whr, const float* __restrict__ bhr,
    const float* __restrict__ Whz, const float* __restrict__ bhz,
    const float* __restrict__ Whh, const float* __restrict__ bhh,
    const float* __restrict__ tw,
    const float* __restrict__ gWih, const float* __restrict__ gWhh,
    const float* __restrict__ gbih, const float* __restrict__ gbhh,
    float* __restrict__ out)
{
    const int tid = threadIdx.x;
    const int j   = tid >> 2;       // output row
    const int q   = tid & 3;        // role within j-group
    const int b0  = blockIdx.x * 2; // batch pair

    __shared__ float hbuf[2][2][NH]; // [pingpong][b][j]
    __shared__ float rh_s[2][NH];    // r*h per flow layer
    __shared__ float x_s[2][ND];     // current xt

    const int kh = (q & 1) * 32;     // 32-wide k-half base
    const int xh = (q & 1) * 16;     // 16-wide x-half base

    // ---------------- one-time weight preload into registers ----------------
    const float* Wrz    = (q < 2) ? Whr : Whz;   // flow gate: r for q<2, z for q>=2
    const float* brzsrc = (q < 2) ? bhr : bhz;

    float wrz[NL][32], wu[NL][16];
    float w65rz[NL], w65u[NL], brz[NL], bu[NL], tws[NL];
#pragma unroll
    for (int l = 0; l < NL; ++l) {
        const int rowrz = (l * NH + j) * (NH + 1);
#pragma unroll
        for (int kk = 0; kk < 32; ++kk) wrz[l][kk] = Wrz[rowrz + kh + kk];
#pragma unroll
        for (int kk = 0; kk < 16; ++kk) wu[l][kk] = Whh[rowrz + q * 16 + kk];
        w65rz[l] = Wrz[rowrz + NH];   // tt column
        w65u[l]  = Whh[rowrz + NH];
        brz[l]   = brzsrc[l * NH + j];
        bu[l]    = bhh[l * NH + j];
        tws[l]   = tw[l * NH + j];
    }

    // GRU pass G1: row = (q<2 ? j : 64+j); i-part 16 wide, h-part 32 wide
    const int g1row = ((q < 2) ? 0 : NH) + j;
    float g1a[16], g1b[32], g2[32];
#pragma unroll
    for (int kk = 0; kk < 16; ++kk) g1a[kk] = gWih[g1row * ND + xh + kk];
#pragma unroll
    for (int kk = 0; kk < 32; ++kk) g1b[kk] = gWhh[g1row * NH + kh + kk];
    // GRU pass G2: q<2 -> h_n halves (row 128+j); q>=2 -> i_n zero-padded to 32
    if (q < 2) {
#pragma unroll
        for (int kk = 0; kk < 32; ++kk) g2[kk] = gWhh[(2 * NH + j) * NH + kh + kk];
    } else {
#pragma unroll
        for (int kk = 0; kk < 32; ++kk) {
            const bool use = (q == 2) ? (kk < 16) : (kk >= 16);
            g2[kk] = use ? gWih[(2 * NH + j) * ND + kk] : 0.0f;
        }
    }
    const float bg1 = gbih[g1row] + gbhh[g1row];
    const float bin = gbih[2 * NH + j];
    const float bhn = gbhh[2 * NH + j];

    if (tid < 2 * NH) (&hbuf[0][0][0])[tid] = 0.0f;  // h0 = 0
    __syncthreads();

    const float* tp0 = tin + b0 * NT;
    const float* tp1 = tin + (b0 + 1) * NT;

    for (int ts = 0; ts < NT; ++ts) {
        const int cur = ts & 1, nxt = cur ^ 1;
        const float tt0 = tp0[ts];          // uniform -> scalar loads
        const float tt1 = tp1[ts];
        float xv = 0.0f;                    // prefetch xt early, consumed late
        if (tid < 64) xv = x[(b0 + (tid >> 5)) * (NT * ND) + ts * ND + (tid & 31)];

        // =================== GRU-flow layers ===================
#pragma unroll
        for (int l = 0; l < NL; ++l) {
            // ---- r/z pass: q<2 computes r (k-half q&1), q>=2 computes z ----
            float a0 = 0.0f, a1 = 0.0f;
            {
                const float* h0p = &hbuf[cur][0][kh];
                const float* h1p = &hbuf[cur][1][kh];
#pragma unroll
                for (int kk = 0; kk < 32; ++kk) {
                    a0 = fmaf(wrz[l][kk], h0p[kk], a0);
                    a1 = fmaf(wrz[l][kk], h1p[kk], a1);
                }
            }
            a0 += __shfl_xor(a0, 1);   // combine k-halves within gate pair
            a1 += __shfl_xor(a1, 1);
            const float s0 = sigm(a0 + w65rz[l] * tt0 + brz[l]);
            const float s1 = sigm(a1 + w65rz[l] * tt1 + brz[l]);
            float zr0 = 0.0f, zr1 = 0.0f;
            if (q < 2) {
                if (q == 0) {          // publish r*h
                    rh_s[0][j] = (ABETA * s0) * hbuf[cur][0][j];
                    rh_s[1][j] = (ABETA * s1) * hbuf[cur][1][j];
                }
            } else {
                zr0 = AALPHA * s0;     // hold z in registers across the barrier
                zr1 = AALPHA * s1;
            }
            __syncthreads();

            // ---- u pass (k-quarter per q) + state update ----
            float u0 = 0.0f, u1 = 0.0f;
            {
                const float* r0p = &rh_s[0][q * 16];
                const float* r1p = &rh_s[1][q * 16];
#pragma unroll
                for (int kk = 0; kk < 16; ++kk) {
                    u0 = fmaf(wu[l][kk], r0p[kk], u0);
                    u1 = fmaf(wu[l][kk], r1p[kk], u1);
                }
            }
            u0 += __shfl_xor(u0, 1); u0 += __shfl_xor(u0, 2);
            u1 += __shfl_xor(u1, 1); u1 += __shfl_xor(u1, 2);
            if (l == NL - 1 && tid < 64)          // stage xt for the GRU cell
                x_s[tid >> 5][tid & 31] = xv;
            const float uu0 = tanh_(u0 + w65u[l] * tt0 + bu[l]);
            const float uu1 = tanh_(u1 + w65u[l] * tt1 + bu[l]);
            if (q >= 2) {
                const float h0 = hbuf[cur][0][j];
                const float h1 = hbuf[cur][1][j];
                const float hn0 = fmaf(tanh_(tws[l] * tt0) * zr0, uu0 - h0, h0);
                const float hn1 = fmaf(tanh_(tws[l] * tt1) * zr1, uu1 - h1, h1);
                if (q == 2) {
                    hbuf[cur][0][j] = hn0;   // in-place: only (j,2)/(j,3) touch [j]
                    hbuf[cur][1][j] = hn1;
                    if (l == NL - 1) {       // hiddens = post-flow, pre-GRU state
                        out[b0 * (NT * NH) + ts * NH + j]       = hn0;
                        out[(b0 + 1) * (NT * NH) + ts * NH + j] = hn1;
                    }
                }
            }
            __syncthreads();
        }

        // =================== GRU cell ===================
        // G1: q0: i_r[0:16)+h_r[0:32) | q1: i_r[16:32)+h_r[32:64) | q2/q3: z likewise
        float p0 = 0.0f, p1 = 0.0f;
        {
            const float* xp0 = &x_s[0][xh];
            const float* xp1 = &x_s[1][xh];
#pragma unroll
            for (int kk = 0; kk < 16; ++kk) {
                p0 = fmaf(g1a[kk], xp0[kk], p0);
                p1 = fmaf(g1a[kk], xp1[kk], p1);
            }
            const float* h0p = &hbuf[cur][0][kh];
            const float* h1p = &hbuf[cur][1][kh];
#pragma unroll
            for (int kk = 0; kk < 32; ++kk) {
                p0 = fmaf(g1b[kk], h0p[kk], p0);
                p1 = fmaf(g1b[kk], h1p[kk], p1);
            }
        }
        p0 += __shfl_xor(p0, 1);
        p1 += __shfl_xor(p1, 1);
        const float gate0 = sigm(p0 + bg1);
        const float gate1 = sigm(p1 + bg1);
        const float oth0 = __shfl_xor(gate0, 2);   // exchange r <-> z
        const float oth1 = __shfl_xor(gate1, 2);
        const float r0 = (q < 2) ? gate0 : oth0;
        const float r1 = (q < 2) ? gate1 : oth1;
        const float z0 = (q < 2) ? oth0 : gate0;
        const float z1 = (q < 2) ? oth1 : gate1;

        // G2: q0/q1: h_n k-halves ; q2/q3: i_n (zero-padded weights over full x)
        float d0 = 0.0f, d1 = 0.0f;
        {
            const float* s0p = (q < 2) ? &hbuf[cur][0][kh] : &x_s[0][0];
            const float* s1p = (q < 2) ? &hbuf[cur][1][kh] : &x_s[1][0];
#pragma unroll
            for (int kk = 0; kk < 32; ++kk) {
                d0 = fmaf(g2[kk], s0p[kk], d0);
                d1 = fmaf(g2[kk], s1p[kk], d1);
            }
        }
        d0 += __shfl_xor(d0, 1);     // {0,1}: h_n dot ; {2,3}: i_n dot
        d1 += __shfl_xor(d1, 1);
        const float e0 = __shfl_xor(d0, 2);        // exchange h_n <-> i_n
        const float e1 = __shfl_xor(d1, 2);
        const float hnd0 = (q < 2) ? d0 : e0;
        const float hnd1 = (q < 2) ? d1 : e1;
        const float ind0 = (q < 2) ? e0 : d0;
        const float ind1 = (q < 2) ? e1 : d1;

        const float n0 = tanh_(ind0 + bin + r0 * (hnd0 + bhn));
        const float n1 = tanh_(ind1 + bin + r1 * (hnd1 + bhn));
        const float h0 = hbuf[cur][0][j];
        const float h1 = hbuf[cur][1][j];
        const float hn0 = (1.0f - z0) * n0 + z0 * h0;
        const float hn1 = (1.0f - z1) * n1 + z1 * h1;
        if (q == 0) {                 // write next-timestep h into ping-pong buf
            hbuf[nxt][0][j] = hn0;
            hbuf[nxt][1][j] = hn1;
        }
        __syncthreads();
    }
}

extern "C" void kernel_launch(void* const* d_in, const int* in_sizes, int n_in,
                              void* d_out, int out_size, void* d_ws, size_t ws_size,
                              hipStream_t stream) {
    const float* x    = (const float*)d_in[0];
    const float* tin  = (const float*)d_in[1];
    const float* Whr  = (const float*)d_in[2];
    const float* bhr  = (const float*)d_in[3];
    const float* Whz  = (const float*)d_in[4];
    const float* bhz  = (const float*)d_in[5];
    const float* Whh  = (const float*)d_in[6];
    const float* bhh  = (const float*)d_in[7];
    const float* tw   = (const float*)d_in[8];
    const float* gWih = (const float*)d_in[9];
    const float* gWhh = (const float*)d_in[10];
    const float* gbih = (const float*)d_in[11];
    const float* gbhh = (const float*)d_in[12];
    float* out = (float*)d_out;

    dim3 grid(NBATCH / 2), block(256);
    hipLaunchKernelGGL(cgru_fused, grid, block, 0, stream,
                       x, tin, Whr, bhr, Whz, bhz, Whh, bhh, tw,
                       gWih, gWhh, gbih, gbhh, out);
}

// Round 3
// 1385.360 us; speedup vs baseline: 1.0395x; 1.0395x over previous
//
#include <hip/hip_runtime.h>

// ContinuousGRULayer: B=512,T=512,D=32,H=64,L=2, fp32.
// Round-3 design: occupancy-first.
//   grid = 512 blocks (1 batch elem each), block = 512 threads = 8 waves.
//   thread (j = tid>>3 in [0,64), q = tid&7): 8-way gate/k split ->
//   per-thread weights ~101 floats -> fits 128-VGPR budget
//   (__launch_bounds__(512,4)) -> 2 blocks/CU = 4 waves/SIMD, and the two
//   co-resident blocks are barrier-independent (latency hiding).
//   LDS state: h[64], rh[64], hx[128] = [h(64) | x(32) | zero-pad(32)].
//   G1/G2 GRU rows are dotted against hx with load-time-reordered weights
//   so every dot is a uniform-length unrolled FMA chain.
//   Roles per j-octet: q0-3 = r-gate (k-quarters), q4-7 = z-gate;
//   u-dot split 8 ways; reductions via __shfl_xor(1,2[,4]).

#define NT 512
#define ND 32
#define NH 64
#define NL 2

__device__ __forceinline__ float sigm(float v) {
    return __builtin_amdgcn_rcpf(1.0f + __expf(-v));
}
__device__ __forceinline__ float tanh_(float v) {
    // tanh(x) = 1 - 2/(1+e^{2x}); saturates correctly at +/-inf
    return 1.0f - 2.0f * __builtin_amdgcn_rcpf(1.0f + __expf(2.0f * v));
}

__global__ __launch_bounds__(512, 4) void cgru_fused(
    const float* __restrict__ x, const float* __restrict__ tin,
    const float* __restrict__ Whr, const float* __restrict__ bhr,
    const float* __restrict__ Whz, const float* __restrict__ bhz,
    const float* __restrict__ Whh, const float* __restrict__ bhh,
    const float* __restrict__ tw,
    const float* __restrict__ gWih, const float* __restrict__ gWhh,
    const float* __restrict__ gbih, const float* __restrict__ gbhh,
    float* __restrict__ out)
{
    const int tid = threadIdx.x;
    const int j   = tid >> 3;      // output row
    const int q   = tid & 7;       // role/k-chunk within row
    const int qh  = q & 3;         // quarter index within gate half
    const bool isZ = q >= 4;
    const int b   = blockIdx.x;    // one batch element per block

    __shared__ float hS[NH];       // current hidden state
    __shared__ float rhS[NH];      // r*h per flow layer
    __shared__ float hxS[128];     // [h(64) | x(32) | zeros(32)]

    // ---------------- one-time weight preload into registers ----------------
    // Flow r/z: q<4 -> W_hr row j (k-quarter qh), q>=4 -> W_hz row j.
    const float* Wsrc = isZ ? Whz : Whr;
    const float* bsrc = isZ ? bhz : bhr;
    float wrz[NL][16], wu[NL][8];
    float w65rz[NL], w65u[NL], brz[NL], bu[NL], tws[NL];
#pragma unroll
    for (int l = 0; l < NL; ++l) {
        const int row = (l * NH + j) * (NH + 1);
#pragma unroll
        for (int k = 0; k < 16; ++k) wrz[l][k] = Wsrc[row + qh * 16 + k];
#pragma unroll
        for (int k = 0; k < 8; ++k)  wu[l][k]  = Whh[row + q * 8 + k];
        w65rz[l] = Wsrc[row + NH];          // tt column
        w65u[l]  = Whh[row + NH];
        brz[l]   = bsrc[l * NH + j];
        bu[l]    = bhh[l * NH + j];
        tws[l]   = tw[l * NH + j];
    }

    // GRU G1: q<4 -> r-row j, q>=4 -> z-row (64+j); dot over hx[0:96) in
    // 24-wide slices, weights reordered to [Whh_row | Wih_row] at load time.
    const int grow = (isZ ? NH : 0) + j;
    float g1[24];
#pragma unroll
    for (int k = 0; k < 24; ++k) {
        const int m = qh * 24 + k;
        g1[k] = (m < NH) ? gWhh[grow * NH + m] : gWih[grow * ND + (m - NH)];
    }
    const float bg1 = gbih[grow] + gbhh[grow];

    // GRU G2 (n-gate row 128+j): q<4 -> h_n 16-wide quarters over hx[0:64),
    // q>=4 -> i_n 8-wide quarters over hx[64:96), zero-padded to 16 so the
    // dot is uniform (pad reads land in hxS[96:128) = zeros).
    float g2[16];
    if (!isZ) {
#pragma unroll
        for (int k = 0; k < 16; ++k) g2[k] = gWhh[(2 * NH + j) * NH + qh * 16 + k];
    } else {
#pragma unroll
        for (int k = 0; k < 8; ++k)  g2[k] = gWih[(2 * NH + j) * ND + qh * 8 + k];
#pragma unroll
        for (int k = 8; k < 16; ++k) g2[k] = 0.0f;
    }
    const float bin = gbih[2 * NH + j];
    const float bhn = gbhh[2 * NH + j];

    if (tid < NH) hS[tid] = 0.0f;           // h0 = 0
    if (tid < 32) hxS[96 + tid] = 0.0f;     // zero pad region (never rewritten)
    __syncthreads();

    const float* xp = x + (size_t)b * NT * ND;
    const float* tp = tin + (size_t)b * NT;
    float* op = out + (size_t)b * NT * NH;

    for (int ts = 0; ts < NT; ++ts) {
        const float tt = tp[ts];                    // uniform across block
        float xv = 0.0f;                            // prefetch xt early
        if (tid < ND) xv = xp[ts * ND + tid];

        // =================== GRU-flow layers ===================
#pragma unroll
        for (int l = 0; l < NL; ++l) {
            // ---- r/z pass: 16-wide k-quarter, q<4 = r, q>=4 = z ----
            float a = 0.0f;
            {
                const float* hp = &hS[qh * 16];
#pragma unroll
                for (int k = 0; k < 16; ++k) a = fmaf(wrz[l][k], hp[k], a);
            }
            a += __shfl_xor(a, 1);
            a += __shfl_xor(a, 2);
            const float s  = sigm(a + w65rz[l] * tt + brz[l]);
            const float zv = 0.4f * s;              // valid on q>=4 lanes
            if (q == 0) rhS[j] = (0.8f * s) * hS[j];
            __syncthreads();

            // ---- u pass: 8-wide k-eighth over r*h ----
            float u = 0.0f;
            {
                const float* rp = &rhS[q * 8];
#pragma unroll
                for (int k = 0; k < 8; ++k) u = fmaf(wu[l][k], rp[k], u);
            }
            u += __shfl_xor(u, 1);
            u += __shfl_xor(u, 2);
            u += __shfl_xor(u, 4);
            if (l == NL - 1 && tid < ND) hxS[NH + tid] = xv;  // stage xt
            const float uu = tanh_(u + w65u[l] * tt + bu[l]);
            if (q == 4) {                           // state update (1 lane/row)
                const float hj = hS[j];
                const float hn = fmaf(tanh_(tws[l] * tt) * zv, uu - hj, hj);
                hS[j] = hn;                         // only (j,4) touches hS[j]
                if (l == NL - 1) {
                    hxS[j] = hn;                    // post-flow h for GRU
                    op[ts * NH + j] = hn;           // hiddens output
                }
            }
            __syncthreads();
        }

        // =================== GRU cell ===================
        // G1: r/z gates, 24-wide slices of hx[0:96)
        float p = 0.0f;
        {
            const float* gp = &hxS[qh * 24];
#pragma unroll
            for (int k = 0; k < 24; ++k) p = fmaf(g1[k], gp[k], p);
        }
        p += __shfl_xor(p, 1);
        p += __shfl_xor(p, 2);
        const float gate = sigm(p + bg1);
        const float oth  = __shfl_xor(gate, 4);     // exchange r <-> z
        const float r = isZ ? oth : gate;
        const float z = isZ ? gate : oth;

        // G2: q<4 -> h_n quarter, q>=4 -> i_n (zero-padded), uniform 16 dot
        float d = 0.0f;
        {
            const float* dp = &hxS[isZ ? (NH + qh * 8) : (qh * 16)];
#pragma unroll
            for (int k = 0; k < 16; ++k) d = fmaf(g2[k], dp[k], d);
        }
        d += __shfl_xor(d, 1);
        d += __shfl_xor(d, 2);
        const float e = __shfl_xor(d, 4);           // exchange h_n <-> i_n
        const float hnd = isZ ? e : d;
        const float ind = isZ ? d : e;

        const float n  = tanh_(ind + bin + r * (hnd + bhn));
        const float hj = hxS[j];                    // post-flow h (broadcast)
        const float hp2 = (1.0f - z) * n + z * hj;
        if (q == 0) hS[j] = hp2;                    // h for next timestep
        __syncthreads();
    }
}

extern "C" void kernel_launch(void* const* d_in, const int* in_sizes, int n_in,
                              void* d_out, int out_size, void* d_ws, size_t ws_size,
                              hipStream_t stream) {
    const float* x    = (const float*)d_in[0];
    const float* tin  = (const float*)d_in[1];
    const float* Whr  = (const float*)d_in[2];
    const float* bhr  = (const float*)d_in[3];
    const float* Whz  = (const float*)d_in[4];
    const float* bhz  = (const float*)d_in[5];
    const float* Whh  = (const float*)d_in[6];
    const float* bhh  = (const float*)d_in[7];
    const float* tw   = (const float*)d_in[8];
    const float* gWih = (const float*)d_in[9];
    const float* gWhh = (const float*)d_in[10];
    const float* gbih = (const float*)d_in[11];
    const float* gbhh = (const float*)d_in[12];
    float* out = (float*)d_out;

    dim3 grid(512), block(512);
    hipLaunchKernelGGL(cgru_fused, grid, block, 0, stream,
                       x, tin, Whr, bhr, Whz, bhz, Whh, bhh, tw,
                       gWih, gWhh, gbih, gbhh, out);
}

// Round 4
// 1383.368 us; speedup vs baseline: 1.0410x; 1.0014x over previous
//
#include <hip/hip_runtime.h>

// ContinuousGRULayer: B=512,T=512,D=32,H=64,L=2, fp32.
// Round-4: register-pinned weights + dual-batch blocks.
//   grid = 256 blocks (2 batch elems each), block = 512 threads = 8 waves,
//   exactly 1 block/CU. thread (j = tid>>3, q = tid&7): 8-way gate/k split.
//   ~101 loop-invariant weight floats per thread, loaded once and PINNED
//   into VGPRs via asm("+v") — round-2/3 showed the allocator otherwise
//   rematerializes them into the t-loop, making the kernel L2-BW-bound
//   (360 KB/CU/ts ≈ 6430 cy/ts, matching the measured 6515 cy/ts).
//   Dual accumulators (batch pair) double FMA per pinned weight and ILP.
//   LDS carries only h/rh/hx state; all state reads are broadcast-class.

#define NT 512
#define ND 32
#define NH 64
#define NL 2

__device__ __forceinline__ float sigm(float v) {
    return __builtin_amdgcn_rcpf(1.0f + __expf(-v));
}
__device__ __forceinline__ float tanh_(float v) {
    // tanh(x) = 1 - 2/(1+e^{2x}); saturates correctly at +/-inf
    return 1.0f - 2.0f * __builtin_amdgcn_rcpf(1.0f + __expf(2.0f * v));
}
// Opaque register pin: forbids rematerialization/sinking of the loaded value.
#define PIN(v) asm volatile("" : "+v"(v))

__global__ __launch_bounds__(512, 2) void cgru_fused(
    const float* __restrict__ x, const float* __restrict__ tin,
    const float* __restrict__ Whr, const float* __restrict__ bhr,
    const float* __restrict__ Whz, const float* __restrict__ bhz,
    const float* __restrict__ Whh, const float* __restrict__ bhh,
    const float* __restrict__ tw,
    const float* __restrict__ gWih, const float* __restrict__ gWhh,
    const float* __restrict__ gbih, const float* __restrict__ gbhh,
    float* __restrict__ out)
{
    const int tid = threadIdx.x;
    const int j   = tid >> 3;      // output row
    const int q   = tid & 7;       // role/k-chunk within row
    const int qh  = q & 3;         // quarter index within gate half
    const bool isZ = q >= 4;
    const int b0  = blockIdx.x * 2;

    __shared__ float hS[2][NH];    // current hidden state per batch elem
    __shared__ float rhS[2][NH];   // r*h per flow layer
    __shared__ float hxS[2][128];  // [h(64) | x(32) | zeros(32)] per batch elem

    // ---------------- one-time weight preload into registers ----------------
    const float* Wsrc = isZ ? Whz : Whr;   // q<4 -> r-gate, q>=4 -> z-gate
    const float* bsrc = isZ ? bhz : bhr;
    float wrz[NL][16], wu[NL][8];
    float w65rz[NL], w65u[NL], brz[NL], bu[NL], tws[NL];
#pragma unroll
    for (int l = 0; l < NL; ++l) {
        const int row = (l * NH + j) * (NH + 1);
#pragma unroll
        for (int k = 0; k < 16; ++k) wrz[l][k] = Wsrc[row + qh * 16 + k];
#pragma unroll
        for (int k = 0; k < 8; ++k)  wu[l][k]  = Whh[row + q * 8 + k];
        w65rz[l] = Wsrc[row + NH];          // tt column
        w65u[l]  = Whh[row + NH];
        brz[l]   = bsrc[l * NH + j];
        bu[l]    = bhh[l * NH + j];
        tws[l]   = tw[l * NH + j];
    }

    // GRU G1 row (r: j / z: 64+j), dot over [h|x] in 24-wide slices,
    // weights reordered to [Whh_row | Wih_row] at load time.
    const int grow = (isZ ? NH : 0) + j;
    float g1[24];
#pragma unroll
    for (int k = 0; k < 24; ++k) {
        const int m = qh * 24 + k;
        g1[k] = (m < NH) ? gWhh[grow * NH + m] : gWih[grow * ND + (m - NH)];
    }
    const float bg1 = gbih[grow] + gbhh[grow];

    // GRU G2 (n-row 128+j): q<4 -> h_n 16-wide quarters; q>=4 -> i_n 8-wide
    // quarters zero-padded to 16 (pad reads land in hxS[96:128) = zeros).
    float g2[16];
    if (!isZ) {
#pragma unroll
        for (int k = 0; k < 16; ++k) g2[k] = gWhh[(2 * NH + j) * NH + qh * 16 + k];
    } else {
#pragma unroll
        for (int k = 0; k < 8; ++k)  g2[k] = gWih[(2 * NH + j) * ND + qh * 8 + k];
#pragma unroll
        for (int k = 8; k < 16; ++k) g2[k] = 0.0f;
    }
    const float bin = gbih[2 * NH + j];
    const float bhn = gbhh[2 * NH + j];

    // ---------------- pin all loop-invariant weights in VGPRs ----------------
#pragma unroll
    for (int l = 0; l < NL; ++l) {
#pragma unroll
        for (int k = 0; k < 16; ++k) PIN(wrz[l][k]);
#pragma unroll
        for (int k = 0; k < 8; ++k)  PIN(wu[l][k]);
        PIN(w65rz[l]); PIN(w65u[l]); PIN(brz[l]); PIN(bu[l]); PIN(tws[l]);
    }
#pragma unroll
    for (int k = 0; k < 24; ++k) PIN(g1[k]);
#pragma unroll
    for (int k = 0; k < 16; ++k) PIN(g2[k]);
    float bg1p = bg1, binp = bin, bhnp = bhn;
    PIN(bg1p); PIN(binp); PIN(bhnp);

    if (tid < 2 * NH) ((float*)hS)[tid] = 0.0f;          // h0 = 0
    if (tid < 2 * ND) hxS[tid >> 5][96 + (tid & 31)] = 0.0f;  // zero pad
    __syncthreads();

    const float* xptr = x + (size_t)(b0 + (tid >= ND ? 1 : 0)) * NT * ND;
    const float* tp0  = tin + (size_t)b0 * NT;
    const float* tp1  = tin + (size_t)(b0 + 1) * NT;
    float* op0 = out + (size_t)b0 * NT * NH;
    float* op1 = out + (size_t)(b0 + 1) * NT * NH;

    // software pipeline: x/t loaded one timestep ahead
    float xv = 0.0f;
    if (tid < 2 * ND) xv = xptr[tid & 31];
    float tt0 = tp0[0], tt1 = tp1[0];

    for (int ts = 0; ts < NT; ++ts) {
        float xnext = 0.0f, ttn0 = 0.0f, ttn1 = 0.0f;
        if (ts + 1 < NT) {
            if (tid < 2 * ND) xnext = xptr[(ts + 1) * ND + (tid & 31)];
            ttn0 = tp0[ts + 1];
            ttn1 = tp1[ts + 1];
        }

        // =================== GRU-flow layers ===================
#pragma unroll
        for (int l = 0; l < NL; ++l) {
            // ---- r/z pass: 16-wide k-quarter; q<4 = r, q>=4 = z ----
            float a0 = 0.0f, a1 = 0.0f;
            {
                const float* hp0 = &hS[0][qh * 16];
                const float* hp1 = &hS[1][qh * 16];
#pragma unroll
                for (int k = 0; k < 16; ++k) {
                    a0 = fmaf(wrz[l][k], hp0[k], a0);
                    a1 = fmaf(wrz[l][k], hp1[k], a1);
                }
            }
            a0 += __shfl_xor(a0, 1); a0 += __shfl_xor(a0, 2);
            a1 += __shfl_xor(a1, 1); a1 += __shfl_xor(a1, 2);
            const float s0 = sigm(a0 + w65rz[l] * tt0 + brz[l]);
            const float s1 = sigm(a1 + w65rz[l] * tt1 + brz[l]);
            const float zv0 = 0.4f * s0;     // valid on q>=4 lanes
            const float zv1 = 0.4f * s1;
            if (q == 0) {                    // publish r*h (r valid on q<4)
                rhS[0][j] = (0.8f * s0) * hS[0][j];
                rhS[1][j] = (0.8f * s1) * hS[1][j];
            }
            __syncthreads();

            // ---- u pass: 8-wide k-eighth over r*h ----
            float u0 = 0.0f, u1 = 0.0f;
            {
                const float* rp0 = &rhS[0][q * 8];
                const float* rp1 = &rhS[1][q * 8];
#pragma unroll
                for (int k = 0; k < 8; ++k) {
                    u0 = fmaf(wu[l][k], rp0[k], u0);
                    u1 = fmaf(wu[l][k], rp1[k], u1);
                }
            }
            u0 += __shfl_xor(u0, 1); u0 += __shfl_xor(u0, 2); u0 += __shfl_xor(u0, 4);
            u1 += __shfl_xor(u1, 1); u1 += __shfl_xor(u1, 2); u1 += __shfl_xor(u1, 4);
            if (l == NL - 1 && tid < 2 * ND)         // stage xt for GRU cell
                hxS[tid >> 5][NH + (tid & 31)] = xv;
            const float uu0 = tanh_(u0 + w65u[l] * tt0 + bu[l]);
            const float uu1 = tanh_(u1 + w65u[l] * tt1 + bu[l]);
            if (q == 4) {                    // state update, 1 lane per row
                const float h0 = hS[0][j];
                const float h1 = hS[1][j];
                const float hn0 = fmaf(tanh_(tws[l] * tt0) * zv0, uu0 - h0, h0);
                const float hn1 = fmaf(tanh_(tws[l] * tt1) * zv1, uu1 - h1, h1);
                hS[0][j] = hn0;
                hS[1][j] = hn1;
                if (l == NL - 1) {           // post-flow state -> GRU input + out
                    hxS[0][j] = hn0;
                    hxS[1][j] = hn1;
                    op0[ts * NH + j] = hn0;
                    op1[ts * NH + j] = hn1;
                }
            }
            __syncthreads();
        }

        // =================== GRU cell ===================
        // G1: r/z gates, 24-wide slices of hx[0:96)
        float p0 = 0.0f, p1 = 0.0f;
        {
            const float* gp0 = &hxS[0][qh * 24];
            const float* gp1 = &hxS[1][qh * 24];
#pragma unroll
            for (int k = 0; k < 24; ++k) {
                p0 = fmaf(g1[k], gp0[k], p0);
                p1 = fmaf(g1[k], gp1[k], p1);
            }
        }
        p0 += __shfl_xor(p0, 1); p0 += __shfl_xor(p0, 2);
        p1 += __shfl_xor(p1, 1); p1 += __shfl_xor(p1, 2);
        const float gate0 = sigm(p0 + bg1p);
        const float gate1 = sigm(p1 + bg1p);
        const float oth0  = __shfl_xor(gate0, 4);    // exchange r <-> z
        const float oth1  = __shfl_xor(gate1, 4);
        const float r0 = isZ ? oth0 : gate0;
        const float r1 = isZ ? oth1 : gate1;
        const float z0 = isZ ? gate0 : oth0;
        const float z1 = isZ ? gate1 : oth1;

        // G2: q<4 -> h_n quarter, q>=4 -> i_n (zero-padded), uniform 16 dot
        float d0 = 0.0f, d1 = 0.0f;
        {
            const int off = isZ ? (NH + qh * 8) : (qh * 16);
            const float* dp0 = &hxS[0][off];
            const float* dp1 = &hxS[1][off];
#pragma unroll
            for (int k = 0; k < 16; ++k) {
                d0 = fmaf(g2[k], dp0[k], d0);
                d1 = fmaf(g2[k], dp1[k], d1);
            }
        }
        d0 += __shfl_xor(d0, 1); d0 += __shfl_xor(d0, 2);
        d1 += __shfl_xor(d1, 1); d1 += __shfl_xor(d1, 2);
        const float e0 = __shfl_xor(d0, 4);          // exchange h_n <-> i_n
        const float e1 = __shfl_xor(d1, 4);
        const float hnd0 = isZ ? e0 : d0;
        const float hnd1 = isZ ? e1 : d1;
        const float ind0 = isZ ? d0 : e0;
        const float ind1 = isZ ? d1 : e1;

        const float n0 = tanh_(ind0 + binp + r0 * (hnd0 + bhnp));
        const float n1 = tanh_(ind1 + binp + r1 * (hnd1 + bhnp));
        const float hj0 = hxS[0][j];                 // post-flow h (broadcast)
        const float hj1 = hxS[1][j];
        const float hp20 = (1.0f - z0) * n0 + z0 * hj0;
        const float hp21 = (1.0f - z1) * n1 + z1 * hj1;
        if (q == 0) {                                // h for next timestep
            hS[0][j] = hp20;
            hS[1][j] = hp21;
        }
        __syncthreads();

        xv = xnext; tt0 = ttn0; tt1 = ttn1;
    }
}

extern "C" void kernel_launch(void* const* d_in, const int* in_sizes, int n_in,
                              void* d_out, int out_size, void* d_ws, size_t ws_size,
                              hipStream_t stream) {
    const float* x    = (const float*)d_in[0];
    const float* tin  = (const float*)d_in[1];
    const float* Whr  = (const float*)d_in[2];
    const float* bhr  = (const float*)d_in[3];
    const float* Whz  = (const float*)d_in[4];
    const float* bhz  = (const float*)d_in[5];
    const float* Whh  = (const float*)d_in[6];
    const float* bhh  = (const float*)d_in[7];
    const float* tw   = (const float*)d_in[8];
    const float* gWih = (const float*)d_in[9];
    const float* gWhh = (const float*)d_in[10];
    const float* gbih = (const float*)d_in[11];
    const float* gbhh = (const float*)d_in[12];
    float* out = (float*)d_out;

    dim3 grid(256), block(512);
    hipLaunchKernelGGL(cgru_fused, grid, block, 0, stream,
                       x, tin, Whr, bhr, Whz, bhz, Whh, bhh, tw,
                       gWih, gWhh, gbih, gbhh, out);
}